// Round 5
// baseline (12831.903 us; speedup 1.0000x reference)
//
#include <hip/hip_runtime.h>

#define T_LEN 256
#define B_SZ  64
#define H_SZ  1024
#define G4H   4096
#define HB    (B_SZ * H_SZ)              // 65536
#define WN    ((size_t)2 * G4H * H_SZ)   // one weight matrix (both layers): 8388608 elems
#define NBLK  256

typedef __attribute__((ext_vector_type(8))) short short8;
typedef __attribute__((ext_vector_type(4))) float float4_;
typedef __attribute__((ext_vector_type(4))) unsigned short ushort4_;

__device__ __forceinline__ unsigned short bf16_rne(float x) {
  unsigned u = __builtin_bit_cast(unsigned, x);
  unsigned r = u + 0x7FFFu + ((u >> 16) & 1u);
  return (unsigned short)(r >> 16);
}
__device__ __forceinline__ float bf16_to_f32(unsigned short s) {
  unsigned u = ((unsigned)s) << 16;
  return __builtin_bit_cast(float, u);
}

// ---------- prep: fp32 weights -> split bf16 hi/lo planes ----------
__global__ __launch_bounds__(256)
void split_w(const float* __restrict__ src, unsigned short* __restrict__ hi,
             unsigned short* __restrict__ lo) {
  const size_t i = ((size_t)blockIdx.x * 256 + threadIdx.x) * 4;
  float4_ v = *(const float4_*)(src + i);
  ushort4_ h, l;
  #pragma unroll
  for (int j = 0; j < 4; ++j) {
    unsigned short hh = bf16_rne(v[j]);
    h[j] = hh;
    l[j] = bf16_rne(v[j] - bf16_to_f32(hh));
  }
  *(ushort4_*)(hi + i) = h;
  *(ushort4_*)(lo + i) = l;
}

// ---------- prep: bias presum ----------
__global__ __launch_bounds__(256)
void presum_bias(const float* __restrict__ bih, const float* __restrict__ bhh,
                 float* __restrict__ bsum) {
  const int i = blockIdx.x * 256 + threadIdx.x;  // grid covers exactly 2*4096
  bsum[i] = bih[i] + bhh[i];
}

// ---------- prep: h0 -> split ring + zero barrier state ----------
__global__ __launch_bounds__(256)
void init_h(const float* __restrict__ h0, unsigned short* __restrict__ rh,
            unsigned short* __restrict__ rl, unsigned* __restrict__ bar) {
  if (blockIdx.x == 0 && threadIdx.x < 16) bar[threadIdx.x] = 0u;
  const int e0 = (blockIdx.x * 256 + threadIdx.x) * 4;
  #pragma unroll
  for (int j = 0; j < 4; ++j) {
    const int e = e0 + j;                 // [2][B][H] = 131072 elems
    const int l = e >> 16;
    const int rem = e & (HB - 1);
    const int slot = (l == 0) ? 1 : 2;    // layer*2 + initial slot
    const float v = h0[e];
    const unsigned short h = bf16_rne(v);
    rh[(size_t)slot * HB + rem] = h;
    rl[(size_t)slot * HB + rem] = bf16_rne(v - bf16_to_f32(h));
  }
}

// ---------- two-level monotonic grid barrier (8 groups x 32 WGs + root) ----------
// bar[0] = root, bar[1..8] = group counters. Monotone: no reset races.
__device__ __forceinline__ void grid_barrier(unsigned* bar, int step) {
  __syncthreads();
  if (threadIdx.x == 0) {
    // release: write back this WG's ring/c stores to the coherence point
    __builtin_amdgcn_fence(__ATOMIC_RELEASE, "agent");
    unsigned* grp = bar + 1 + (blockIdx.x >> 5);
    unsigned a = __hip_atomic_fetch_add(grp, 1u, __ATOMIC_RELEASE, __HIP_MEMORY_SCOPE_AGENT);
    if ((a & 31u) == 31u) {  // last of this group's 32 arrivals for this step
      __hip_atomic_fetch_add(bar, 1u, __ATOMIC_RELEASE, __HIP_MEMORY_SCOPE_AGENT);
    }
    const unsigned target = (unsigned)(step + 1) * 8u;
    while (__hip_atomic_load(bar, __ATOMIC_RELAXED, __HIP_MEMORY_SCOPE_AGENT) < target) {
      __builtin_amdgcn_s_sleep(2);
    }
    // acquire: invalidate stale L1/L2 lines so we see other XCDs' ring writes
    __builtin_amdgcn_fence(__ATOMIC_ACQUIRE, "agent");
  }
  __syncthreads();
}

// ---------- persistent LSTM: weights register-resident, custom grid sync ----------
// 256 WGs x 256 thr, 1 block/CU (co-resident by grid<=CUs). wg>>7 = layer,
// wg&127 = cb (8 hcols = 32 gate cols = 2 MFMA n-tiles, i/f/g/o permuted).
// 4 waves split K (256 each); LDS reduce; fused elementwise; split-bf16 h ring.
__global__ __launch_bounds__(256, 1)
void lstm_persist(const float* __restrict__ x_in,
                  const float* __restrict__ c0_in,
                  const unsigned short* __restrict__ whi,   // [mat][L][4H][H] bf16-hi
                  const unsigned short* __restrict__ wlo,
                  const float* __restrict__ bsum,           // [L][4H]
                  unsigned short* __restrict__ ring_hi,     // [2L*2slots][B][H]
                  unsigned short* __restrict__ ring_lo,
                  float* __restrict__ c_ws,                 // [L][B][H]
                  float* __restrict__ out,
                  unsigned* __restrict__ bar)
{
  const int wg    = blockIdx.x;
  const int layer = wg >> 7;
  const int cb    = wg & 127;
  const int tid   = threadIdx.x;
  const int lane  = tid & 63;
  const int wave  = tid >> 6;
  const int nn    = lane & 15;
  const int quad  = lane >> 4;

  __shared__ float lds[4][64][34];  // [wave][b][ncol]; stride 34 -> max 2-way (free)

  // gate rows for this lane's two n-tiles
  int growA[2];
  #pragma unroll
  for (int nt = 0; nt < 2; ++nt) {
    const int q = nt * 2 + (nn >> 3);
    growA[nt] = q * H_SZ + cb * 8 + (nn & 7);
  }

  // ---- one-time: weights -> registers (256 VGPRs/lane of split-bf16 B-fragments)
  short8 wreg[2][2][2][8];  // [mat(ih,hh)][plane(hi,lo)][ntile][kb]
  #pragma unroll
  for (int mat = 0; mat < 2; ++mat)
    #pragma unroll
    for (int nt = 0; nt < 2; ++nt)
      #pragma unroll
      for (int kb = 0; kb < 8; ++kb) {
        const size_t b0 = (mat ? WN : (size_t)0) +
                          ((size_t)layer * G4H + growA[nt]) * H_SZ +
                          wave * 256 + kb * 32 + quad * 8;
        wreg[mat][0][nt][kb] = *(const short8*)(whi + b0);
        wreg[mat][1][nt][kb] = *(const short8*)(wlo + b0);
      }

  // ---- pipelined recurrence: step s: layer0 does t=s, layer1 does t=s-1 ----
  for (int s = 0; s <= T_LEN; ++s) {
    const bool active = (layer == 0) ? (s < T_LEN) : (s >= 1);
    if (active) {
      const int sl = (s - 1) & 1;  // ring slot written at step s-1 (init in slot 1)
      const unsigned short* hhi = ring_hi + (size_t)(layer * 2 + sl) * HB;
      const unsigned short* hlo = ring_lo + (size_t)(layer * 2 + sl) * HB;
      const float* xf = x_in + (size_t)s * HB;               // layer0 input (fp32)
      const unsigned short* xhi = ring_hi + (size_t)sl * HB; // layer1 input = layer0 h
      const unsigned short* xlo = ring_lo + (size_t)sl * HB;

      float4_ acc[4][2];
      #pragma unroll
      for (int m = 0; m < 4; ++m)
        #pragma unroll
        for (int nt = 0; nt < 2; ++nt)
          acc[m][nt] = float4_{0.f, 0.f, 0.f, 0.f};

      #pragma unroll
      for (int kb = 0; kb < 8; ++kb) {
        const int k0 = wave * 256 + kb * 32 + quad * 8;
        #pragma unroll
        for (int m = 0; m < 4; ++m) {
          const int row = m * 16 + nn;
          short8 ahi, alo;
          if (layer == 0) {
            const float* p = xf + (size_t)row * H_SZ + k0;
            #pragma unroll
            for (int j = 0; j < 8; ++j) {
              const float v = p[j];
              const unsigned short h = bf16_rne(v);
              ahi[j] = (short)h;
              alo[j] = (short)bf16_rne(v - bf16_to_f32(h));
            }
          } else {
            ahi = *(const short8*)(xhi + (size_t)row * H_SZ + k0);
            alo = *(const short8*)(xlo + (size_t)row * H_SZ + k0);
          }
          const short8 bhi = *(const short8*)(hhi + (size_t)row * H_SZ + k0);
          const short8 blo = *(const short8*)(hlo + (size_t)row * H_SZ + k0);
          #pragma unroll
          for (int nt = 0; nt < 2; ++nt) {
            acc[m][nt] = __builtin_amdgcn_mfma_f32_16x16x32_bf16(ahi, wreg[0][0][nt][kb], acc[m][nt], 0, 0, 0);
            acc[m][nt] = __builtin_amdgcn_mfma_f32_16x16x32_bf16(alo, wreg[0][0][nt][kb], acc[m][nt], 0, 0, 0);
            acc[m][nt] = __builtin_amdgcn_mfma_f32_16x16x32_bf16(ahi, wreg[0][1][nt][kb], acc[m][nt], 0, 0, 0);
            acc[m][nt] = __builtin_amdgcn_mfma_f32_16x16x32_bf16(bhi, wreg[1][0][nt][kb], acc[m][nt], 0, 0, 0);
            acc[m][nt] = __builtin_amdgcn_mfma_f32_16x16x32_bf16(blo, wreg[1][0][nt][kb], acc[m][nt], 0, 0, 0);
            acc[m][nt] = __builtin_amdgcn_mfma_f32_16x16x32_bf16(bhi, wreg[1][1][nt][kb], acc[m][nt], 0, 0, 0);
          }
        }
      }

      // partials -> LDS. C/D layout: col = lane&15 (n), row = quad*4+reg (batch)
      #pragma unroll
      for (int m = 0; m < 4; ++m)
        #pragma unroll
        for (int nt = 0; nt < 2; ++nt)
          #pragma unroll
          for (int r = 0; r < 4; ++r)
            lds[wave][m * 16 + quad * 4 + r][nt * 16 + nn] = acc[m][nt][r];
      __syncthreads();

      // reduce over 4 K-slice waves + fused elementwise; 2 (b,hcol) pairs/thread
      #pragma unroll
      for (int pp = 0; pp < 2; ++pp) {
        const int p    = tid + pp * 256;
        const int b    = p >> 3;
        const int hc   = p & 7;
        const int hcol = cb * 8 + hc;
        float g[4];
        #pragma unroll
        for (int q = 0; q < 4; ++q) {
          const int ncol = q * 8 + hc;
          float sum = lds[0][b][ncol] + lds[1][b][ncol] + lds[2][b][ncol] + lds[3][b][ncol];
          sum += bsum[layer * G4H + q * H_SZ + hcol];
          g[q] = sum;
        }
        const size_t cidx  = (size_t)layer * HB + (size_t)b * H_SZ + hcol;
        const bool  cfirst = (layer == 0) ? (s == 0) : (s == 1);
        const float cprev  = cfirst ? c0_in[cidx] : c_ws[cidx];
        const float ig = 1.f / (1.f + __expf(-g[0]));
        const float fg = 1.f / (1.f + __expf(-g[1]));
        const float gg = tanhf(g[2]);
        const float og = 1.f / (1.f + __expf(-g[3]));
        const float cn = fg * cprev + ig * gg;
        const float hn = og * tanhf(cn);
        c_ws[cidx] = cn;
        const size_t ridx = (size_t)(layer * 2 + (s & 1)) * HB + (size_t)b * H_SZ + hcol;
        const unsigned short hh = bf16_rne(hn);
        ring_hi[ridx] = hh;
        ring_lo[ridx] = bf16_rne(hn - bf16_to_f32(hh));
        if (layer == 1 && s == T_LEN) out[(size_t)b * H_SZ + hcol] = hn;
      }
    }
    grid_barrier(bar, s);  // unconditional: all 256 WGs arrive every step
  }
}

extern "C" void kernel_launch(void* const* d_in, const int* in_sizes, int n_in,
                              void* d_out, int out_size, void* d_ws, size_t ws_size,
                              hipStream_t stream) {
  (void)in_sizes; (void)n_in; (void)out_size; (void)ws_size;
  const float* x   = (const float*)d_in[0];
  const float* h0  = (const float*)d_in[1];
  const float* c0  = (const float*)d_in[2];
  const float* Wih = (const float*)d_in[3];
  const float* Whh = (const float*)d_in[4];
  const float* bih = (const float*)d_in[5];
  const float* bhh = (const float*)d_in[6];
  float* out = (float*)d_out;

  // workspace layout (~69 MB)
  char* w = (char*)d_ws;
  unsigned short* whi     = (unsigned short*)w;                         // 2*WN shorts
  unsigned short* wlo     = (unsigned short*)(w + 2 * WN * 2);
  unsigned short* ring_hi = (unsigned short*)(w + 4 * WN * 2);          // 4*HB shorts
  unsigned short* ring_lo = (unsigned short*)(w + 4 * WN * 2 + (size_t)4 * HB * 2);
  float*          c_ws    = (float*)(w + 4 * WN * 2 + (size_t)8 * HB * 2);
  float*          bsum    = (float*)(w + 4 * WN * 2 + (size_t)8 * HB * 2 + (size_t)2 * HB * 4);
  unsigned*       bar     = (unsigned*)(w + 4 * WN * 2 + (size_t)8 * HB * 2 + (size_t)2 * HB * 4
                                        + (size_t)2 * G4H * 4);

  // prep (graph-captured each call): split weights, bias presum, ring + barrier init
  split_w<<<(int)(WN / 4 / 256), 256, 0, stream>>>(Wih, whi, wlo);
  split_w<<<(int)(WN / 4 / 256), 256, 0, stream>>>(Whh, whi + WN, wlo + WN);
  presum_bias<<<2 * G4H / 256, 256, 0, stream>>>(bih, bhh, bsum);
  init_h<<<2 * HB / 4 / 256, 256, 0, stream>>>(h0, ring_hi, ring_lo, bar);

  // persistent kernel: 256 blocks <= 256 CUs -> all co-resident, custom grid barrier
  lstm_persist<<<NBLK, 256, 0, stream>>>(x, c0, whi, wlo, bsum,
                                         ring_hi, ring_lo, c_ws, out, bar);
}

// Round 6
// 8287.759 us; speedup vs baseline: 1.5483x; 1.5483x over previous
//
#include <hip/hip_runtime.h>

#define T_LEN 256
#define B_SZ  64
#define H_SZ  1024
#define G4H   4096
#define HB    (B_SZ * H_SZ)              // 65536
#define WN    ((size_t)2 * G4H * H_SZ)   // one weight matrix (both layers): 8388608 elems
#define NBLK  256

typedef __attribute__((ext_vector_type(8))) short short8;
typedef __attribute__((ext_vector_type(4))) float float4_;
typedef __attribute__((ext_vector_type(4))) unsigned short ushort4_;
typedef __attribute__((ext_vector_type(8))) unsigned int uint8_;

__device__ __forceinline__ unsigned short bf16_rne(float x) {
  unsigned u = __builtin_bit_cast(unsigned, x);
  unsigned r = u + 0x7FFFu + ((u >> 16) & 1u);
  return (unsigned short)(r >> 16);
}
__device__ __forceinline__ float bf16_to_f32(unsigned short s) {
  unsigned u = ((unsigned)s) << 16;
  return __builtin_bit_cast(float, u);
}

// ---------- prep: fp32 weights -> split bf16 hi/lo planes ----------
__global__ __launch_bounds__(256)
void split_w(const float* __restrict__ src, unsigned short* __restrict__ hi,
             unsigned short* __restrict__ lo) {
  const size_t i = ((size_t)blockIdx.x * 256 + threadIdx.x) * 4;
  float4_ v = *(const float4_*)(src + i);
  ushort4_ h, l;
  #pragma unroll
  for (int j = 0; j < 4; ++j) {
    unsigned short hh = bf16_rne(v[j]);
    h[j] = hh;
    l[j] = bf16_rne(v[j] - bf16_to_f32(hh));
  }
  *(ushort4_*)(hi + i) = h;
  *(ushort4_*)(lo + i) = l;
}

// ---------- prep: bias presum ----------
__global__ __launch_bounds__(256)
void presum_bias(const float* __restrict__ bih, const float* __restrict__ bhh,
                 float* __restrict__ bsum) {
  const int i = blockIdx.x * 256 + threadIdx.x;  // grid covers exactly 2*4096
  bsum[i] = bih[i] + bhh[i];
}

// ---------- prep: h0 -> packed split ring + zero barrier state ----------
__global__ __launch_bounds__(256)
void init_h(const float* __restrict__ h0, unsigned* __restrict__ ringp,
            unsigned* __restrict__ bar) {
  if (blockIdx.x == 0) {
    #pragma unroll
    for (int j = 0; j < 4; ++j) bar[threadIdx.x * 4 + j] = 0u;
  }
  const int e0 = (blockIdx.x * 256 + threadIdx.x) * 4;
  #pragma unroll
  for (int j = 0; j < 4; ++j) {
    const int e = e0 + j;                 // [2][B][H] = 131072 elems
    const int l = e >> 16;
    const int rem = e & (HB - 1);
    const int slot = (l == 0) ? 1 : 2;    // ring index layer*2 + initial slot
    const float v = h0[e];
    const unsigned hh = bf16_rne(v);
    const unsigned ll = bf16_rne(v - bf16_to_f32((unsigned short)hh));
    ringp[(size_t)slot * HB + rem] = hh | (ll << 16);
  }
}

// ---------- grid barrier: no data fences except one acquire-inv ----------
// bar layout (uints, 128B-padded lines): [0] root; [32*(1+g)] group-g arrivals;
// [32*(9+g)] group-g go flag.  Monotone counters, no resets.
// Ring stores are agent-scope atomics (L3-coherent); __syncthreads drains vmcnt
// before arrival, so arrivals imply ring data is in L3. The acquire fence after
// exit invalidates L1/L2 so this step's reads refill fresh from L3.
__device__ __forceinline__ void grid_barrier(unsigned* bar, int step) {
  __syncthreads();   // compiler emits s_waitcnt vmcnt(0) before s_barrier: ring stores drained
  if (threadIdx.x == 0) {
    const int g = blockIdx.x >> 5;
    unsigned* grp = bar + 32 * (1 + g);
    unsigned* go  = bar + 32 * (9 + g);
    const unsigned t1 = (unsigned)step + 1u;
    __builtin_amdgcn_s_waitcnt(0);
    unsigned a = __hip_atomic_fetch_add(grp, 1u, __ATOMIC_RELAXED, __HIP_MEMORY_SCOPE_AGENT);
    if ((a & 31u) == 31u) {  // 32nd arrival of this step: group leader
      __hip_atomic_fetch_add(bar, 1u, __ATOMIC_RELAXED, __HIP_MEMORY_SCOPE_AGENT);
      while (__hip_atomic_load(bar, __ATOMIC_RELAXED, __HIP_MEMORY_SCOPE_AGENT) < 8u * t1)
        __builtin_amdgcn_s_sleep(2);
      __hip_atomic_store(go, t1, __ATOMIC_RELAXED, __HIP_MEMORY_SCOPE_AGENT);
    } else {
      while (__hip_atomic_load(go, __ATOMIC_RELAXED, __HIP_MEMORY_SCOPE_AGENT) < t1)
        __builtin_amdgcn_s_sleep(2);
    }
    __builtin_amdgcn_fence(__ATOMIC_ACQUIRE, "agent");  // inv L1/L2: fresh ring reads
  }
  __syncthreads();
}

// ---------- persistent LSTM: weights register/AGPR-resident ----------
// 256 WGs x 256 thr, 1 block/CU. wg>>7 = layer, wg&127 = cb (8 hcols = 32 gate
// cols = 2 MFMA n-tiles, i/f/g/o permuted). 4 waves split K (256 each); LDS
// reduce; fused elementwise; c in registers; packed h ring via agent atomics.
__global__ __launch_bounds__(256, 1)
void lstm_persist(const float* __restrict__ x_in,
                  const float* __restrict__ c0_in,
                  const unsigned short* __restrict__ whi,   // [mat][L][4H][H] bf16-hi
                  const unsigned short* __restrict__ wlo,
                  const float* __restrict__ bsum,           // [L][4H]
                  unsigned* __restrict__ ringp,             // [2L*2slots][B][H] packed hi|lo
                  float* __restrict__ out,
                  unsigned* __restrict__ bar)
{
  const int wg    = blockIdx.x;
  const int layer = wg >> 7;
  const int cb    = wg & 127;
  const int tid   = threadIdx.x;
  const int lane  = tid & 63;
  const int wave  = tid >> 6;
  const int nn    = lane & 15;
  const int quad  = lane >> 4;

  __shared__ float lds[4][64][34];  // [wave][b][ncol]; stride 34 -> max 2-way (free)

  // gate rows for this lane's two n-tiles
  int growA[2];
  #pragma unroll
  for (int nt = 0; nt < 2; ++nt) {
    const int q = nt * 2 + (nn >> 3);
    growA[nt] = q * H_SZ + cb * 8 + (nn & 7);
  }

  // ---- one-time: weights -> registers (1 KB/lane of split-bf16 B-fragments)
  short8 wreg[2][2][2][8];  // [mat(ih,hh)][plane(hi,lo)][ntile][kb]
  #pragma unroll
  for (int mat = 0; mat < 2; ++mat)
    #pragma unroll
    for (int nt = 0; nt < 2; ++nt)
      #pragma unroll
      for (int kb = 0; kb < 8; ++kb) {
        const size_t b0 = (mat ? WN : (size_t)0) +
                          ((size_t)layer * G4H + growA[nt]) * H_SZ +
                          wave * 256 + kb * 32 + quad * 8;
        wreg[mat][0][nt][kb] = *(const short8*)(whi + b0);
        wreg[mat][1][nt][kb] = *(const short8*)(wlo + b0);
      }

  // ---- per-thread register c state (2 fixed (b,hcol) pairs per thread)
  float creg[2];

  // ---- pipelined recurrence: step s: layer0 does t=s, layer1 does t=s-1 ----
  for (int s = 0; s <= T_LEN; ++s) {
    const bool active = (layer == 0) ? (s < T_LEN) : (s >= 1);
    if (active) {
      const int sl = (s - 1) & 1;  // ring slot written at step s-1 (init in slot 1)
      const unsigned* hq = ringp + (size_t)(layer * 2 + sl) * HB;  // own-layer h
      const unsigned* xq = ringp + (size_t)sl * HB;                // layer0 h (layer1 input)
      const float*    xf = x_in + (size_t)s * HB;                  // fp32 input (layer0)

      float4_ acc[4][2];
      #pragma unroll
      for (int m = 0; m < 4; ++m)
        #pragma unroll
        for (int nt = 0; nt < 2; ++nt)
          acc[m][nt] = float4_{0.f, 0.f, 0.f, 0.f};

      #pragma unroll
      for (int kb = 0; kb < 8; ++kb) {
        const int k0 = wave * 256 + kb * 32 + quad * 8;
        #pragma unroll
        for (int m = 0; m < 4; ++m) {
          const int row = m * 16 + nn;
          short8 ahi, alo;
          if (layer == 0) {
            const float* p = xf + (size_t)row * H_SZ + k0;
            #pragma unroll
            for (int j = 0; j < 8; ++j) {
              const float v = p[j];
              const unsigned short h = bf16_rne(v);
              ahi[j] = (short)h;
              alo[j] = (short)bf16_rne(v - bf16_to_f32(h));
            }
          } else {
            const uint8_ u = *(const uint8_*)(xq + (size_t)row * H_SZ + k0);
            #pragma unroll
            for (int j = 0; j < 8; ++j) {
              ahi[j] = (short)(u[j] & 0xffffu);
              alo[j] = (short)(u[j] >> 16);
            }
          }
          const uint8_ v8 = *(const uint8_*)(hq + (size_t)row * H_SZ + k0);
          short8 bhi, blo;
          #pragma unroll
          for (int j = 0; j < 8; ++j) {
            bhi[j] = (short)(v8[j] & 0xffffu);
            blo[j] = (short)(v8[j] >> 16);
          }
          #pragma unroll
          for (int nt = 0; nt < 2; ++nt) {
            acc[m][nt] = __builtin_amdgcn_mfma_f32_16x16x32_bf16(ahi, wreg[0][0][nt][kb], acc[m][nt], 0, 0, 0);
            acc[m][nt] = __builtin_amdgcn_mfma_f32_16x16x32_bf16(alo, wreg[0][0][nt][kb], acc[m][nt], 0, 0, 0);
            acc[m][nt] = __builtin_amdgcn_mfma_f32_16x16x32_bf16(ahi, wreg[0][1][nt][kb], acc[m][nt], 0, 0, 0);
            acc[m][nt] = __builtin_amdgcn_mfma_f32_16x16x32_bf16(bhi, wreg[1][0][nt][kb], acc[m][nt], 0, 0, 0);
            acc[m][nt] = __builtin_amdgcn_mfma_f32_16x16x32_bf16(blo, wreg[1][0][nt][kb], acc[m][nt], 0, 0, 0);
            acc[m][nt] = __builtin_amdgcn_mfma_f32_16x16x32_bf16(bhi, wreg[1][1][nt][kb], acc[m][nt], 0, 0, 0);
          }
        }
      }

      // partials -> LDS. C/D layout: col = lane&15 (n), row = quad*4+reg (batch)
      #pragma unroll
      for (int m = 0; m < 4; ++m)
        #pragma unroll
        for (int nt = 0; nt < 2; ++nt)
          #pragma unroll
          for (int r = 0; r < 4; ++r)
            lds[wave][m * 16 + quad * 4 + r][nt * 16 + nn] = acc[m][nt][r];
      __syncthreads();

      // reduce over 4 K-slice waves + fused elementwise; 2 (b,hcol) pairs/thread
      #pragma unroll
      for (int pp = 0; pp < 2; ++pp) {
        const int p    = tid + pp * 256;
        const int b    = p >> 3;
        const int hc   = p & 7;
        const int hcol = cb * 8 + hc;
        float g[4];
        #pragma unroll
        for (int q = 0; q < 4; ++q) {
          const int ncol = q * 8 + hc;
          float sum = lds[0][b][ncol] + lds[1][b][ncol] + lds[2][b][ncol] + lds[3][b][ncol];
          sum += bsum[layer * G4H + q * H_SZ + hcol];
          g[q] = sum;
        }
        const bool  cfirst = (layer == 0) ? (s == 0) : (s == 1);
        const float cprev  = cfirst
            ? c0_in[(size_t)layer * HB + (size_t)b * H_SZ + hcol]
            : creg[pp];
        const float ig = 1.f / (1.f + __expf(-g[0]));
        const float fg = 1.f / (1.f + __expf(-g[1]));
        const float gg = tanhf(g[2]);
        const float og = 1.f / (1.f + __expf(-g[3]));
        const float cn = fg * cprev + ig * gg;
        const float hn = og * tanhf(cn);
        creg[pp] = cn;
        const size_t ridx = (size_t)(layer * 2 + (s & 1)) * HB + (size_t)b * H_SZ + hcol;
        const unsigned hh = bf16_rne(hn);
        const unsigned ll = bf16_rne(hn - bf16_to_f32((unsigned short)hh));
        __hip_atomic_store(&ringp[ridx], hh | (ll << 16),
                           __ATOMIC_RELAXED, __HIP_MEMORY_SCOPE_AGENT);
        if (layer == 1 && s == T_LEN) out[(size_t)b * H_SZ + hcol] = hn;
      }
    }
    grid_barrier(bar, s);  // unconditional: all 256 WGs arrive every step
  }
}

extern "C" void kernel_launch(void* const* d_in, const int* in_sizes, int n_in,
                              void* d_out, int out_size, void* d_ws, size_t ws_size,
                              hipStream_t stream) {
  (void)in_sizes; (void)n_in; (void)out_size; (void)ws_size;
  const float* x   = (const float*)d_in[0];
  const float* h0  = (const float*)d_in[1];
  const float* c0  = (const float*)d_in[2];
  const float* Wih = (const float*)d_in[3];
  const float* Whh = (const float*)d_in[4];
  const float* bih = (const float*)d_in[5];
  const float* bhh = (const float*)d_in[6];
  float* out = (float*)d_out;

  // workspace layout (~68.3 MB)
  char* w = (char*)d_ws;
  unsigned short* whi   = (unsigned short*)w;                          // 2*WN shorts = 32 MB
  unsigned short* wlo   = (unsigned short*)(w + 2 * WN * 2);           // 32 MB
  unsigned*       ringp = (unsigned*)(w + 4 * WN * 2);                 // 4*HB uints = 1 MB
  float*          bsum  = (float*)(w + 4 * WN * 2 + (size_t)4 * HB * 4);   // 32 KB
  unsigned*       bar   = (unsigned*)(w + 4 * WN * 2 + (size_t)4 * HB * 4
                                      + (size_t)2 * G4H * 4);          // 4 KB

  // prep (graph-captured each call): split weights, bias presum, ring + barrier init
  split_w<<<(int)(WN / 4 / 256), 256, 0, stream>>>(Wih, whi, wlo);
  split_w<<<(int)(WN / 4 / 256), 256, 0, stream>>>(Whh, whi + WN, wlo + WN);
  presum_bias<<<2 * G4H / 256, 256, 0, stream>>>(bih, bhh, bsum);
  init_h<<<2 * HB / 4 / 256, 256, 0, stream>>>(h0, ringp, bar);

  // persistent kernel: 256 blocks <= 256 CUs -> all co-resident, custom grid barrier
  lstm_persist<<<NBLK, 256, 0, stream>>>(x, c0, whi, wlo, bsum, ringp, out, bar);
}

// Round 7
// 5585.434 us; speedup vs baseline: 2.2974x; 1.4838x over previous
//
#include <hip/hip_runtime.h>

#define T_LEN 256
#define B_SZ  64
#define H_SZ  1024
#define G4H   4096
#define HB    (B_SZ * H_SZ)              // 65536
#define WN    ((size_t)2 * G4H * H_SZ)   // one weight matrix (both layers): 8388608 elems
#define NBLK  256

typedef __attribute__((ext_vector_type(8))) short short8;
typedef __attribute__((ext_vector_type(4))) float float4_;
typedef __attribute__((ext_vector_type(4))) unsigned short ushort4_;
typedef __attribute__((ext_vector_type(8))) unsigned int uint8_;

__device__ __forceinline__ unsigned short bf16_rne(float x) {
  unsigned u = __builtin_bit_cast(unsigned, x);
  unsigned r = u + 0x7FFFu + ((u >> 16) & 1u);
  return (unsigned short)(r >> 16);
}
__device__ __forceinline__ float bf16_to_f32(unsigned short s) {
  unsigned u = ((unsigned)s) << 16;
  return __builtin_bit_cast(float, u);
}

// ---------- prep: fp32 weights -> split bf16 hi/lo planes ----------
__global__ __launch_bounds__(256)
void split_w(const float* __restrict__ src, unsigned short* __restrict__ hi,
             unsigned short* __restrict__ lo) {
  const size_t i = ((size_t)blockIdx.x * 256 + threadIdx.x) * 4;
  float4_ v = *(const float4_*)(src + i);
  ushort4_ h, l;
  #pragma unroll
  for (int j = 0; j < 4; ++j) {
    unsigned short hh = bf16_rne(v[j]);
    h[j] = hh;
    l[j] = bf16_rne(v[j] - bf16_to_f32(hh));
  }
  *(ushort4_*)(hi + i) = h;
  *(ushort4_*)(lo + i) = l;
}

// ---------- prep: bias presum ----------
__global__ __launch_bounds__(256)
void presum_bias(const float* __restrict__ bih, const float* __restrict__ bhh,
                 float* __restrict__ bsum) {
  const int i = blockIdx.x * 256 + threadIdx.x;  // grid covers exactly 2*4096
  bsum[i] = bih[i] + bhh[i];
}

// ---------- prep: h0 -> packed split ring + zero barrier state ----------
__global__ __launch_bounds__(256)
void init_h(const float* __restrict__ h0, unsigned* __restrict__ ringp,
            unsigned* __restrict__ bar) {
  if (blockIdx.x == 0) {
    #pragma unroll
    for (int j = 0; j < 4; ++j) bar[threadIdx.x * 4 + j] = 0u;
  }
  const int e0 = (blockIdx.x * 256 + threadIdx.x) * 4;
  #pragma unroll
  for (int j = 0; j < 4; ++j) {
    const int e = e0 + j;                 // [2][B][H] = 131072 elems
    const int l = e >> 16;
    const int rem = e & (HB - 1);
    const int slot = (l == 0) ? 1 : 2;    // ring index layer*2 + initial slot
    const float v = h0[e];
    const unsigned hh = bf16_rne(v);
    const unsigned ll = bf16_rne(v - bf16_to_f32((unsigned short)hh));
    ringp[(size_t)slot * HB + rem] = hh | (ll << 16);
  }
}

// ---------- grid barrier (two-level, monotone, padded lines) ----------
__device__ __forceinline__ void grid_barrier(unsigned* bar, int step) {
  __syncthreads();   // drains vmcnt: ring stores visible at coherence point
  if (threadIdx.x == 0) {
    const int g = blockIdx.x >> 5;
    unsigned* grp = bar + 32 * (1 + g);
    unsigned* go  = bar + 32 * (9 + g);
    const unsigned t1 = (unsigned)step + 1u;
    __builtin_amdgcn_s_waitcnt(0);
    unsigned a = __hip_atomic_fetch_add(grp, 1u, __ATOMIC_RELAXED, __HIP_MEMORY_SCOPE_AGENT);
    if ((a & 31u) == 31u) {  // 32nd arrival of this step: group leader
      __hip_atomic_fetch_add(bar, 1u, __ATOMIC_RELAXED, __HIP_MEMORY_SCOPE_AGENT);
      while (__hip_atomic_load(bar, __ATOMIC_RELAXED, __HIP_MEMORY_SCOPE_AGENT) < 8u * t1)
        __builtin_amdgcn_s_sleep(2);
      __hip_atomic_store(go, t1, __ATOMIC_RELAXED, __HIP_MEMORY_SCOPE_AGENT);
    } else {
      while (__hip_atomic_load(go, __ATOMIC_RELAXED, __HIP_MEMORY_SCOPE_AGENT) < t1)
        __builtin_amdgcn_s_sleep(2);
    }
    __builtin_amdgcn_fence(__ATOMIC_ACQUIRE, "agent");  // inv L1/L2: fresh ring reads
  }
  __syncthreads();
}

// ---------- persistent LSTM: 256 WGs x 512 thr (2 waves/SIMD) ----------
// wg>>7 = layer, wg&127 = cb (8 hcols = 32 gate cols = 2 MFMA n-tiles, i/f/g/o
// permuted). 8 waves split K (128 each); per-lane weights 64 VGPR; LDS reduce
// over 8 waves; fused elementwise (1 pair/thread); c in regs; packed h ring.
__global__ __launch_bounds__(512, 2)
void lstm_persist(const float* __restrict__ x_in,
                  const float* __restrict__ c0_in,
                  const unsigned short* __restrict__ whi,   // [mat][L][4H][H] bf16-hi
                  const unsigned short* __restrict__ wlo,
                  const float* __restrict__ bsum,           // [L][4H]
                  unsigned* __restrict__ ringp,             // [2L*2slots][B][H] packed hi|lo
                  float* __restrict__ out,
                  unsigned* __restrict__ bar)
{
  const int wg    = blockIdx.x;
  const int layer = wg >> 7;
  const int cb    = wg & 127;
  const int tid   = threadIdx.x;
  const int lane  = tid & 63;
  const int wave  = tid >> 6;    // 0..7 : K-slice of 128
  const int nn    = lane & 15;
  const int quad  = lane >> 4;

  __shared__ float lds[8][64][34];  // [wave][b][ncol]; 69.6 KB

  // gate rows for this lane's two n-tiles
  int growA[2];
  #pragma unroll
  for (int nt = 0; nt < 2; ++nt) {
    const int q = nt * 2 + (nn >> 3);
    growA[nt] = q * H_SZ + cb * 8 + (nn & 7);
  }

  // ---- one-time: weights -> registers (512 B/lane of split-bf16 B-fragments)
  short8 wreg[2][2][2][4];  // [mat(ih,hh)][plane(hi,lo)][ntile][kb]
  #pragma unroll
  for (int mat = 0; mat < 2; ++mat)
    #pragma unroll
    for (int nt = 0; nt < 2; ++nt)
      #pragma unroll
      for (int kb = 0; kb < 4; ++kb) {
        const size_t b0 = (mat ? WN : (size_t)0) +
                          ((size_t)layer * G4H + growA[nt]) * H_SZ +
                          wave * 128 + kb * 32 + quad * 8;
        wreg[mat][0][nt][kb] = *(const short8*)(whi + b0);
        wreg[mat][1][nt][kb] = *(const short8*)(wlo + b0);
      }

  // ---- per-thread register c state (1 fixed (b,hcol) pair per thread)
  float creg = 0.f;

  // ---- pipelined recurrence: step s: layer0 does t=s, layer1 does t=s-1 ----
  for (int s = 0; s <= T_LEN; ++s) {
    const bool active = (layer == 0) ? (s < T_LEN) : (s >= 1);
    if (active) {
      const int sl = (s - 1) & 1;  // ring slot written at step s-1 (init in slot 1)
      const unsigned* hq = ringp + (size_t)(layer * 2 + sl) * HB;  // own-layer h
      const unsigned* xq = ringp + (size_t)sl * HB;                // layer0 h (layer1 input)
      const float*    xf = x_in + (size_t)s * HB;                  // fp32 input (layer0)

      float4_ acc[4][2];
      #pragma unroll
      for (int m = 0; m < 4; ++m)
        #pragma unroll
        for (int nt = 0; nt < 2; ++nt)
          acc[m][nt] = float4_{0.f, 0.f, 0.f, 0.f};

      #pragma unroll
      for (int kb = 0; kb < 4; ++kb) {
        const int k0 = wave * 128 + kb * 32 + quad * 8;
        #pragma unroll
        for (int m = 0; m < 4; ++m) {
          const int row = m * 16 + nn;
          short8 ahi, alo;
          if (layer == 0) {
            const float* p = xf + (size_t)row * H_SZ + k0;
            #pragma unroll
            for (int j = 0; j < 8; ++j) {
              const float v = p[j];
              const unsigned short h = bf16_rne(v);
              ahi[j] = (short)h;
              alo[j] = (short)bf16_rne(v - bf16_to_f32(h));
            }
          } else {
            const uint8_ u = *(const uint8_*)(xq + (size_t)row * H_SZ + k0);
            #pragma unroll
            for (int j = 0; j < 8; ++j) {
              ahi[j] = (short)(u[j] & 0xffffu);
              alo[j] = (short)(u[j] >> 16);
            }
          }
          const uint8_ v8 = *(const uint8_*)(hq + (size_t)row * H_SZ + k0);
          short8 bhi, blo;
          #pragma unroll
          for (int j = 0; j < 8; ++j) {
            bhi[j] = (short)(v8[j] & 0xffffu);
            blo[j] = (short)(v8[j] >> 16);
          }
          #pragma unroll
          for (int nt = 0; nt < 2; ++nt) {
            acc[m][nt] = __builtin_amdgcn_mfma_f32_16x16x32_bf16(ahi, wreg[0][0][nt][kb], acc[m][nt], 0, 0, 0);
            acc[m][nt] = __builtin_amdgcn_mfma_f32_16x16x32_bf16(alo, wreg[0][0][nt][kb], acc[m][nt], 0, 0, 0);
            acc[m][nt] = __builtin_amdgcn_mfma_f32_16x16x32_bf16(ahi, wreg[0][1][nt][kb], acc[m][nt], 0, 0, 0);
            acc[m][nt] = __builtin_amdgcn_mfma_f32_16x16x32_bf16(bhi, wreg[1][0][nt][kb], acc[m][nt], 0, 0, 0);
            acc[m][nt] = __builtin_amdgcn_mfma_f32_16x16x32_bf16(blo, wreg[1][0][nt][kb], acc[m][nt], 0, 0, 0);
            acc[m][nt] = __builtin_amdgcn_mfma_f32_16x16x32_bf16(bhi, wreg[1][1][nt][kb], acc[m][nt], 0, 0, 0);
          }
        }
      }

      // partials -> LDS. C/D layout: col = lane&15 (n), row = quad*4+reg (batch)
      #pragma unroll
      for (int m = 0; m < 4; ++m)
        #pragma unroll
        for (int nt = 0; nt < 2; ++nt)
          #pragma unroll
          for (int r = 0; r < 4; ++r)
            lds[wave][m * 16 + quad * 4 + r][nt * 16 + nn] = acc[m][nt][r];
      __syncthreads();

      // reduce over 8 K-slice waves + fused elementwise; 1 (b,hcol) pair/thread
      {
        const int b    = tid >> 3;
        const int hc   = tid & 7;
        const int hcol = cb * 8 + hc;
        float g[4];
        #pragma unroll
        for (int q = 0; q < 4; ++q) {
          const int ncol = q * 8 + hc;
          float sum = 0.f;
          #pragma unroll
          for (int w = 0; w < 8; ++w) sum += lds[w][b][ncol];
          sum += bsum[layer * G4H + q * H_SZ + hcol];
          g[q] = sum;
        }
        const bool  cfirst = (layer == 0) ? (s == 0) : (s == 1);
        const float cprev  = cfirst
            ? c0_in[(size_t)layer * HB + (size_t)b * H_SZ + hcol]
            : creg;
        const float ig = 1.f / (1.f + __expf(-g[0]));
        const float fg = 1.f / (1.f + __expf(-g[1]));
        const float gg = tanhf(g[2]);
        const float og = 1.f / (1.f + __expf(-g[3]));
        const float cn = fg * cprev + ig * gg;
        const float hn = og * tanhf(cn);
        creg = cn;
        const size_t ridx = (size_t)(layer * 2 + (s & 1)) * HB + (size_t)b * H_SZ + hcol;
        const unsigned hh = bf16_rne(hn);
        const unsigned ll = bf16_rne(hn - bf16_to_f32((unsigned short)hh));
        __hip_atomic_store(&ringp[ridx], hh | (ll << 16),
                           __ATOMIC_RELAXED, __HIP_MEMORY_SCOPE_AGENT);
        if (layer == 1 && s == T_LEN) out[(size_t)b * H_SZ + hcol] = hn;
      }
    }
    grid_barrier(bar, s);  // unconditional: all 256 WGs arrive every step
  }
}

extern "C" void kernel_launch(void* const* d_in, const int* in_sizes, int n_in,
                              void* d_out, int out_size, void* d_ws, size_t ws_size,
                              hipStream_t stream) {
  (void)in_sizes; (void)n_in; (void)out_size; (void)ws_size;
  const float* x   = (const float*)d_in[0];
  const float* h0  = (const float*)d_in[1];
  const float* c0  = (const float*)d_in[2];
  const float* Wih = (const float*)d_in[3];
  const float* Whh = (const float*)d_in[4];
  const float* bih = (const float*)d_in[5];
  const float* bhh = (const float*)d_in[6];
  float* out = (float*)d_out;

  // workspace layout (~68.3 MB)
  char* w = (char*)d_ws;
  unsigned short* whi   = (unsigned short*)w;                          // 2*WN shorts = 32 MB
  unsigned short* wlo   = (unsigned short*)(w + 2 * WN * 2);           // 32 MB
  unsigned*       ringp = (unsigned*)(w + 4 * WN * 2);                 // 4*HB uints = 1 MB
  float*          bsum  = (float*)(w + 4 * WN * 2 + (size_t)4 * HB * 4);   // 32 KB
  unsigned*       bar   = (unsigned*)(w + 4 * WN * 2 + (size_t)4 * HB * 4
                                      + (size_t)2 * G4H * 4);          // 4 KB

  // prep (graph-captured each call): split weights, bias presum, ring + barrier init
  split_w<<<(int)(WN / 4 / 256), 256, 0, stream>>>(Wih, whi, wlo);
  split_w<<<(int)(WN / 4 / 256), 256, 0, stream>>>(Whh, whi + WN, wlo + WN);
  presum_bias<<<2 * G4H / 256, 256, 0, stream>>>(bih, bhh, bsum);
  init_h<<<2 * HB / 4 / 256, 256, 0, stream>>>(h0, ringp, bar);

  // persistent kernel: 256 blocks <= 256 CUs, 512 thr (8 waves, 2/SIMD)
  lstm_persist<<<NBLK, 512, 0, stream>>>(x, c0, whi, wlo, bsum, ringp, out, bar);
}